// Round 9
// baseline (75.125 us; speedup 1.0000x reference)
//
#include <hip/hip_runtime.h>
#include <math.h>

// DRR via Siddon ray tracing, 256^3 volume, 256x256 detector.
// Wave = 64 consecutive rays at the SAME alpha-partition (coalesced volume
// loads: ~4-8 cache lines per wave-instant in the native x-major layout).
// Block = 256 threads = 4 such waves (4 consecutive partitions = adjacent
// x-slabs). No intra-block reduction: each thread atomically accumulates its
// partial (x raylength) into out[ray]; out is zeroed via hipMemsetAsync.
// Cells derived per-segment via midpoint-trunc (bit-faithful to reference
// rounding). Out-of-range plane alphas exceed amax by >= one alpha-quantum,
// so plane-advance needs no range checks.

#define NPLANE 256
constexpr int TPR = 16;

__device__ __forceinline__ float palpha(int i, float sp, float src, float rd) {
    return fmaf((float)i, sp, -src) * rd;
}
__device__ __forceinline__ float palpha_f(float fi, float sp, float nsrc, float rd) {
    return fmaf(fi, sp, nsrc) * rd;
}

__global__ __launch_bounds__(256) void drr_kernel(
    const float* __restrict__ vol,
    const float* __restrict__ spacing,
    const float* __restrict__ sdrp,
    const float* __restrict__ rot,
    const float* __restrict__ trans,
    float* __restrict__ out)
{
    int tid   = threadIdx.x;
    int b     = blockIdx.x;
    int part  = ((b & 3) << 2) | (tid >> 6);      // 0..15
    int rlane = tid & 63;
    int rl    = ((b >> 2) << 6) | rlane;          // 0..65535 linear ray id

    // R = Rz(theta) @ Ry(phi) @ Rx(gamma): columns 0 (ray dir), 1 (u), 2 (v)
    float theta = rot[0], phi = rot[1], gam = rot[2];
    float ct = cosf(theta), st = sinf(theta);
    float cp = cosf(phi),   sp_ = sinf(phi);
    float cg = cosf(gam),   sg = sinf(gam);

    float r0x = ct * cp, r0y = st * cp, r0z = -sp_;
    float ux = ct * sp_ * sg - st * cg, uy = st * sp_ * sg + ct * cg, uz = cp * sg;
    float vx = ct * sp_ * cg + st * sg, vy = st * sp_ * cg - ct * sg, vz = cp * cg;

    // lane-fast detector axis = least stride-weighted volume motion (uniform)
    float cost_u = fabsf(ux) * 65536.f + fabsf(uy) * 256.f + fabsf(uz);
    float cost_v = fabsf(vx) * 65536.f + fabsf(vy) * 256.f + fabsf(vz);
    bool tfast = cost_u < cost_v;
    int ti = tfast ? (rl & 255) : (rl >> 8);
    int si = tfast ? (rl >> 8) : (rl & 255);

    float sdr = sdrp[0];
    float tx = trans[0], ty = trans[1], tz = trans[2];

    float sx = sdr * r0x + tx,  sy = sdr * r0y + ty,  sz = sdr * r0z + tz;
    float cxx = -sdr * r0x + tx, cxy = -sdr * r0y + ty, cxz = -sdr * r0z + tz;

    float tval = (float)(ti - 127) * 2.0f;
    float sval = (float)(si - 127) * 2.0f;

    float gx = tval * ux + sval * vx + cxx;
    float gy = tval * uy + sval * vy + cxy;
    float gz = tval * uz + sval * vz + cxz;

    float sdx = gx - sx + 1e-8f;
    float sdy = gy - sy + 1e-8f;
    float sdz = gz - sz + 1e-8f;

    float spx = spacing[0], spy = spacing[1], spz = spacing[2];
    float rdx = 1.0f / sdx, rdy = 1.0f / sdy, rdz = 1.0f / sdz;

    float a0x = palpha(0, spx, sx, rdx), a1x = palpha(NPLANE, spx, sx, rdx);
    float a0y = palpha(0, spy, sy, rdy), a1y = palpha(NPLANE, spy, sy, rdy);
    float a0z = palpha(0, spz, sz, rdz), a1z = palpha(NPLANE, spz, sz, rdz);

    float amin = fmaxf(fmaxf(fminf(a0x, a1x), fminf(a0y, a1y)), fminf(a0z, a1z));
    float amax = fminf(fminf(fmaxf(a0x, a1x), fmaxf(a0y, a1y)), fmaxf(a0z, a1z));

    float acc = 0.f;

    if (amax > amin) {
        float range = amax - amin;
        constexpr float inv = 1.0f / (float)TPR;
        float lo = fmaf(range, (float)part * inv, amin);
        float hi = (part == TPR - 1) ? INFINITY
                                     : fmaf(range, (float)(part + 1) * inv, amin);
        float end = fminf(hi, amax);

        int iix, iiy, iiz, dix, diy, diz;
        float nxx, nxy, nxz;

        // first plane crossing with alpha >= lo per axis
        #define SETUP(SP, SRC, SDD, RD, I, DI, NXT)                                \
        {                                                                          \
            float q = fmaf(lo, SDD, SRC) / (SP);                                   \
            q = fminf(fmaxf(q, -1.f), 257.f);                                      \
            if ((SDD) > 0.f) {                                                     \
                DI = 1;                                                            \
                I = (int)ceilf(q);                                                 \
                while (I > 0 && palpha(I - 1, SP, SRC, RD) >= lo) --I;             \
                while (I <= NPLANE && palpha(I, SP, SRC, RD) < lo) ++I;            \
                NXT = (I <= NPLANE) ? palpha(I, SP, SRC, RD) : INFINITY;           \
            } else {                                                               \
                DI = -1;                                                           \
                I = (int)floorf(q);                                                \
                while (I < NPLANE && palpha(I + 1, SP, SRC, RD) >= lo) ++I;        \
                while (I >= 0 && palpha(I, SP, SRC, RD) < lo) --I;                 \
                NXT = (I >= 0) ? palpha(I, SP, SRC, RD) : INFINITY;                \
            }                                                                      \
        }

        SETUP(spx, sx, sdx, rdx, iix, dix, nxx)
        SETUP(spy, sy, sdy, rdy, iiy, diy, nxy)
        SETUP(spz, sz, sdz, rdz, iiz, diz, nxz)
        #undef SETUP

        float fix = (float)iix, fiy = (float)iiy, fiz = (float)iiz;
        float dfx = (float)dix, dfy = (float)diy, dfz = (float)diz;
        float nsx = -sx, nsy = -sy, nsz = -sz;

        // 1/spacing: at spacing==1 this is exactly 1.0 and *1.0 is an IEEE
        // identity, so positions match the reference's division bit-for-bit.
        float ispx = 1.0f / spx, ispy = 1.0f / spy, ispz = 1.0f / spz;

        #define ADV()                                                              \
            if (nxx == cur) { fix += dfx; nxx = palpha_f(fix, spx, nsx, rdx); }    \
            if (nxy == cur) { fiy += dfy; nxy = palpha_f(fiy, spy, nsy, rdy); }    \
            if (nxz == cur) { fiz += dfz; nxz = palpha_f(fiz, spz, nsz, rdz); }

        #define SEG(CUR, E, ADDR)                                                  \
        {                                                                          \
            float amid = 0.5f * ((CUR) + (E));                                     \
            float pxv = fmaf(amid, sdx, sx) * ispx;                                \
            float pyv = fmaf(amid, sdy, sy) * ispy;                                \
            float pzv = fmaf(amid, sdz, sz) * ispz;                                \
            int jx = (int)pxv; jx = jx < 0 ? 0 : (jx > 255 ? 255 : jx);            \
            int jy = (int)pyv; jy = jy < 0 ? 0 : (jy > 255 ? 255 : jy);            \
            int jz = (int)pzv; jz = jz < 0 ? 0 : (jz > 255 ? 255 : jz);            \
            ADDR = (jx << 16) + (jy << 8) + jz;                                    \
        }

        float cur = fminf(fminf(nxx, nxy), nxz);

        if (cur < end) {
            ADV();
            float nxt = fminf(fminf(nxx, nxy), nxz);
            float e   = fminf(nxt, amax);
            int a; SEG(cur, e, a)
            float sA = e - cur;
            float vA = vol[a];
            cur = nxt;

            while (cur < end) {
                ADV();
                nxt = fminf(fminf(nxx, nxy), nxz);
                e   = fminf(nxt, amax);
                SEG(cur, e, a)
                float vB = vol[a];                 // issue B
                acc = fmaf(vA, sA, acc);           // consume A
                float sB = e - cur;
                cur = nxt;
                if (cur >= end) { acc = fmaf(vB, sB, acc); goto traced; }

                ADV();
                nxt = fminf(fminf(nxx, nxy), nxz);
                e   = fminf(nxt, amax);
                SEG(cur, e, a)
                vA = vol[a];                       // issue A'
                acc = fmaf(vB, sB, acc);           // consume B
                sA = e - cur;
                cur = nxt;
            }
            acc = fmaf(vA, sA, acc);               // drain
            traced: ;
        }
        #undef ADV
        #undef SEG
    }

    // one partial per thread; 16 partials land per output element
    float rl2 = sqrtf(sdx * sdx + sdy * sdy + sdz * sdz);
    if (acc != 0.f)
        atomicAdd(&out[ti * 256 + si], acc * rl2);
}

extern "C" void kernel_launch(void* const* d_in, const int* in_sizes, int n_in,
                              void* d_out, int out_size, void* d_ws, size_t ws_size,
                              hipStream_t stream) {
    const float* vol     = (const float*)d_in[0];
    const float* spacing = (const float*)d_in[1];
    const float* sdr     = (const float*)d_in[2];
    const float* rot     = (const float*)d_in[3];
    const float* trans   = (const float*)d_in[4];
    float* out = (float*)d_out;

    hipMemsetAsync(out, 0, (size_t)out_size * sizeof(float), stream);

    int nblocks = 256 * 256 * TPR / 256;   // 4096 blocks of 256 threads
    drr_kernel<<<nblocks, 256, 0, stream>>>(vol, spacing, sdr, rot, trans, out);
}

// Round 10
// 60.013 us; speedup vs baseline: 1.2518x; 1.2518x over previous
//
#include <hip/hip_runtime.h>
#include <math.h>

// DRR via Siddon ray tracing, 256^3 volume, 256x256 detector.
// Block = 256 threads = 16 consecutive rays (lane-fast, contiguous along the
// volume's fast z-axis) x 16 alpha-partitions (slow). A wave holds 16 rays x 4
// adjacent x-slab partitions -> each volume-load instant touches ~4-12 cache
// lines (vs ~64 with partition-fast lanes), and the block's 4 waves share one
// 16-ray tube in L1/L2. Reduction: shfl_xor folds 4 partitions per wave, a
// 64-float LDS tile folds the 4 waves. Inner loop identical to the proven R6
// loop (midpoint-trunc cells, bit-faithful to reference rounding; depth-1
// software pipeline).

#define NPLANE 256
constexpr int TPR = 16;

__device__ __forceinline__ float palpha(int i, float sp, float src, float rd) {
    return fmaf((float)i, sp, -src) * rd;
}

__global__ __launch_bounds__(256) void drr_kernel(
    const float* __restrict__ vol,
    const float* __restrict__ spacing,
    const float* __restrict__ sdrp,
    const float* __restrict__ rot,
    const float* __restrict__ trans,
    float* __restrict__ out)
{
    int tid  = threadIdx.x;
    int part = tid >> 4;                    // 0..15 (slow)
    int rlo  = tid & 15;                    // ray-in-block (fast)
    int rl   = ((int)blockIdx.x << 4) | rlo;   // 0..65535 linear ray id

    // R = Rz(theta) @ Ry(phi) @ Rx(gamma): columns 0 (ray dir), 1 (u), 2 (v)
    float theta = rot[0], phi = rot[1], gam = rot[2];
    float ct = cosf(theta), st = sinf(theta);
    float cp = cosf(phi),   sp_ = sinf(phi);
    float cg = cosf(gam),   sg = sinf(gam);

    float r0x = ct * cp, r0y = st * cp, r0z = -sp_;
    float ux = ct * sp_ * sg - st * cg, uy = st * sp_ * sg + ct * cg, uz = cp * sg;
    float vx = ct * sp_ * cg + st * sg, vy = st * sp_ * cg - ct * sg, vz = cp * cg;

    // lane-fast detector axis = least stride-weighted volume motion (uniform)
    float cost_u = fabsf(ux) * 65536.f + fabsf(uy) * 256.f + fabsf(uz);
    float cost_v = fabsf(vx) * 65536.f + fabsf(vy) * 256.f + fabsf(vz);
    bool tfast = cost_u < cost_v;
    int ti = tfast ? (rl & 255) : (rl >> 8);
    int si = tfast ? (rl >> 8) : (rl & 255);

    float sdr = sdrp[0];
    float tx = trans[0], ty = trans[1], tz = trans[2];

    float sx = sdr * r0x + tx,  sy = sdr * r0y + ty,  sz = sdr * r0z + tz;
    float cxx = -sdr * r0x + tx, cxy = -sdr * r0y + ty, cxz = -sdr * r0z + tz;

    float tval = (float)(ti - 127) * 2.0f;
    float sval = (float)(si - 127) * 2.0f;

    float gx = tval * ux + sval * vx + cxx;
    float gy = tval * uy + sval * vy + cxy;
    float gz = tval * uz + sval * vz + cxz;

    float sdx = gx - sx + 1e-8f;
    float sdy = gy - sy + 1e-8f;
    float sdz = gz - sz + 1e-8f;

    float spx = spacing[0], spy = spacing[1], spz = spacing[2];
    float rdx = 1.0f / sdx, rdy = 1.0f / sdy, rdz = 1.0f / sdz;

    float a0x = palpha(0, spx, sx, rdx), a1x = palpha(NPLANE, spx, sx, rdx);
    float a0y = palpha(0, spy, sy, rdy), a1y = palpha(NPLANE, spy, sy, rdy);
    float a0z = palpha(0, spz, sz, rdz), a1z = palpha(NPLANE, spz, sz, rdz);

    float amin = fmaxf(fmaxf(fminf(a0x, a1x), fminf(a0y, a1y)), fminf(a0z, a1z));
    float amax = fminf(fminf(fmaxf(a0x, a1x), fmaxf(a0y, a1y)), fmaxf(a0z, a1z));

    float acc = 0.f;

    if (amax > amin) {
        float range = amax - amin;
        constexpr float inv = 1.0f / (float)TPR;
        float lo = fmaf(range, (float)part * inv, amin);
        float hi = (part == TPR - 1) ? INFINITY
                                     : fmaf(range, (float)(part + 1) * inv, amin);
        float end = fminf(hi, amax);

        int ix, iy, iz, dix, diy, diz;
        float nxx, nxy, nxz;

        // first plane crossing with alpha >= lo per axis
        #define SETUP(SP, SRC, SDD, RD, I, DI, NXT)                                \
        {                                                                          \
            float q = fmaf(lo, SDD, SRC) / (SP);                                   \
            q = fminf(fmaxf(q, -1.f), 257.f);                                      \
            if ((SDD) > 0.f) {                                                     \
                DI = 1;                                                            \
                I = (int)ceilf(q);                                                 \
                while (I > 0 && palpha(I - 1, SP, SRC, RD) >= lo) --I;             \
                while (I <= NPLANE && palpha(I, SP, SRC, RD) < lo) ++I;            \
                NXT = (I <= NPLANE) ? palpha(I, SP, SRC, RD) : INFINITY;           \
            } else {                                                               \
                DI = -1;                                                           \
                I = (int)floorf(q);                                                \
                while (I < NPLANE && palpha(I + 1, SP, SRC, RD) >= lo) ++I;        \
                while (I >= 0 && palpha(I, SP, SRC, RD) < lo) --I;                 \
                NXT = (I >= 0) ? palpha(I, SP, SRC, RD) : INFINITY;                \
            }                                                                      \
        }

        SETUP(spx, sx, sdx, rdx, ix, dix, nxx)
        SETUP(spy, sy, sdy, rdy, iy, diy, nxy)
        SETUP(spz, sz, sdz, rdz, iz, diz, nxz)
        #undef SETUP

        float ispx = 1.0f / spx, ispy = 1.0f / spy, ispz = 1.0f / spz;

        #define ADVANCE_MERGE()                                                    \
            if (nxx == cur) { ix += dix;                                           \
                nxx = ((unsigned)ix <= NPLANE) ? palpha(ix, spx, sx, rdx)          \
                                               : INFINITY; }                       \
            if (nxy == cur) { iy += diy;                                           \
                nxy = ((unsigned)iy <= NPLANE) ? palpha(iy, spy, sy, rdy)          \
                                               : INFINITY; }                       \
            if (nxz == cur) { iz += diz;                                           \
                nxz = ((unsigned)iz <= NPLANE) ? palpha(iz, spz, sz, rdz)          \
                                               : INFINITY; }

        #define SEG_ADDR(CUR, E, ADDR)                                             \
        {                                                                          \
            float amid = 0.5f * ((CUR) + (E));                                     \
            float pxv = fmaf(amid, sdx, sx) * ispx;                                \
            float pyv = fmaf(amid, sdy, sy) * ispy;                                \
            float pzv = fmaf(amid, sdz, sz) * ispz;                                \
            int jx = (int)pxv; jx = jx < 0 ? 0 : (jx > 255 ? 255 : jx);            \
            int jy = (int)pyv; jy = jy < 0 ? 0 : (jy > 255 ? 255 : jy);            \
            int jz = (int)pzv; jz = jz < 0 ? 0 : (jz > 255 ? 255 : jz);            \
            ADDR = (jx << 16) + (jy << 8) + jz;                                    \
        }

        float cur = fminf(fminf(nxx, nxy), nxz);

        if (cur < end) {
            // peel: compute segment 0, issue its load
            ADVANCE_MERGE();
            float nxt = fminf(fminf(nxx, nxy), nxz);
            float e   = fminf(nxt, amax);
            int addr; SEG_ADDR(cur, e, addr)
            float pstep = e - cur;
            float pval  = vol[addr];
            cur = nxt;

            while (cur < end) {
                // advance to segment n+1, issue its load while load n in flight
                ADVANCE_MERGE();
                nxt = fminf(fminf(nxx, nxy), nxz);
                e   = fminf(nxt, amax);
                int addr2; SEG_ADDR(cur, e, addr2)
                float nval = vol[addr2];           // issue (vmcnt grows)
                acc = fmaf(pval, pstep, acc);      // consume load n (vmcnt(1))
                pval  = nval;
                pstep = e - cur;
                cur = nxt;
            }
            acc = fmaf(pval, pstep, acc);          // drain
        }
        #undef ADVANCE_MERGE
        #undef SEG_ADDR
    }

    // reduction: fold the wave's 4 partitions (lanes r, r+16, r+32, r+48),
    // then the block's 4 waves via a 64-float LDS tile.
    acc += __shfl_xor(acc, 16);
    acc += __shfl_xor(acc, 32);

    __shared__ float red[64];
    int wave = tid >> 6;                     // 0..3
    if ((tid & 63) < 16)
        red[(wave << 4) | rlo] = acc;
    __syncthreads();

    if (tid < 16) {
        float s = red[tid] + red[16 + tid] + red[32 + tid] + red[48 + tid];
        float rl2 = sqrtf(sdx * sdx + sdy * sdy + sdz * sdz);
        out[ti * 256 + si] = s * rl2;
    }
}

extern "C" void kernel_launch(void* const* d_in, const int* in_sizes, int n_in,
                              void* d_out, int out_size, void* d_ws, size_t ws_size,
                              hipStream_t stream) {
    const float* vol     = (const float*)d_in[0];
    const float* spacing = (const float*)d_in[1];
    const float* sdr     = (const float*)d_in[2];
    const float* rot     = (const float*)d_in[3];
    const float* trans   = (const float*)d_in[4];
    float* out = (float*)d_out;

    int nblocks = 256 * 256 / 16;   // 4096 blocks x 256 threads (16 rays each)
    drr_kernel<<<nblocks, 256, 0, stream>>>(vol, spacing, sdr, rot, trans, out);
}